// Round 5
// baseline (4490.129 us; speedup 1.0000x reference)
//
#include <hip/hip_runtime.h>
#include <hip/hip_bf16.h>

typedef __hip_bfloat16 bf16;

#define BSZ 32
#define TT  128
#define IC  16
#define NDIM 512
#define KT  32   // output-column tile per block
#define NC  64   // reduction chunk staged in LDS

__device__ __forceinline__ float sigf(float v) { return 1.0f / (1.0f + expf(-v)); }

// Inputs fp32, output fp32 (reference dtype). No d_ws usage. Recurrent state
// lives inside d_out (fp32):
//   h[t-1] == out[:, t-1] slice  (exactly the graded output value)
//   c      == c_fin slot (single-buffered; each element read+written only by
//             its owning thread; the t=127 write is the graded c_fin)
// t==0 reads no prior state, so harness re-poisoning of d_out is safe.
__launch_bounds__(256)
__global__ void step_kernel(int t,
    const float* __restrict__ x,
    const float* __restrict__ Uj, const float* __restrict__ Ui, const float* __restrict__ Uf, const float* __restrict__ Uo,
    const float* __restrict__ Wj, const float* __restrict__ Wi, const float* __restrict__ Wf, const float* __restrict__ Wo,
    const float* __restrict__ bj, const float* __restrict__ bi, const float* __restrict__ bfp, const float* __restrict__ bo,
    float* __restrict__ out)
{
    // w_lds[nn][k*4+g] : 4 gate weights interleaved; one float4 read -> all gates
    __shared__ float w_lds[NC][KT * 4 + 4];   // row stride 132 floats (528B, 16B-mult)
    __shared__ float h_lds[NC][BSZ + 4];      // row stride 36 floats (144B, 16B-mult)

    const int i   = blockIdx.x;          // channel 0..15
    const int k0  = blockIdx.y * KT;     // column tile base
    const int tid = threadIdx.x;
    const int kl  = tid & 31;            // local column
    const int bg  = tid >> 5;            // batch group 0..7 (4 rows each)
    const int kg  = k0 + kl;             // global column

    float* hfin = out + (size_t)BSZ * TT * IC * NDIM;
    float* cfin = hfin + (size_t)BSZ * IC * NDIM;

    // accumulators: acc[gate][j], j -> batch row bg*4+j
    float acc[4][4];
    {
        size_t uidx = (size_t)i * NDIM + kg;
        float u0 = Uj[uidx], u1 = Ui[uidx], u2 = Uf[uidx], u3 = Uo[uidx];
        float c0 = bj[uidx], c1 = bi[uidx], c2 = bfp[uidx], c3 = bo[uidx];
        #pragma unroll
        for (int j = 0; j < 4; j++) {
            int b = bg * 4 + j;
            float xv = x[(size_t)(b * TT + t) * IC + i];
            acc[0][j] = c0 + xv * u0;
            acc[1][j] = c1 + xv * u1;
            acc[2][j] = c2 + xv * u2;
            acc[3][j] = c3 + xv * u3;
        }
    }

    if (t > 0) {
        for (int n0 = 0; n0 < NDIM; n0 += NC) {
            __syncthreads();
            // ---- stage W chunk (fp32): thread -> (gate g, row nn), 32 columns
            {
                int g  = tid >> 6;   // wave-uniform
                int nn = tid & 63;
                const float* Wp = (g == 0) ? Wj : (g == 1) ? Wi : (g == 2) ? Wf : Wo;
                const float4* p = (const float4*)(Wp + ((size_t)i * NDIM + (size_t)(n0 + nn)) * NDIM + k0);
                #pragma unroll
                for (int q = 0; q < 8; q++) {
                    float4 v = p[q];
                    w_lds[nn][(q * 4 + 0) * 4 + g] = v.x;
                    w_lds[nn][(q * 4 + 1) * 4 + g] = v.y;
                    w_lds[nn][(q * 4 + 2) * 4 + g] = v.z;
                    w_lds[nn][(q * 4 + 3) * 4 + g] = v.w;
                }
            }
            // ---- stage h chunk from out[:, t-1] (fp32): thread -> (batch b, 8 n)
            {
                int b  = tid >> 3;
                int nb = (tid & 7) * 8;
                const float4* ph = (const float4*)(out +
                    ((size_t)(b * TT + (t - 1)) * IC + i) * NDIM + n0 + nb);
                float4 h0 = ph[0], h1 = ph[1];
                h_lds[nb + 0][b] = h0.x;
                h_lds[nb + 1][b] = h0.y;
                h_lds[nb + 2][b] = h0.z;
                h_lds[nb + 3][b] = h0.w;
                h_lds[nb + 4][b] = h1.x;
                h_lds[nb + 5][b] = h1.y;
                h_lds[nb + 6][b] = h1.z;
                h_lds[nb + 7][b] = h1.w;
            }
            __syncthreads();

            // ---- inner product over the chunk
            #pragma unroll 8
            for (int nn = 0; nn < NC; nn++) {
                float4 wv = *(const float4*)&w_lds[nn][kl * 4];   // gates j,i,f,o at col kg
                float4 hv = *(const float4*)&h_lds[nn][bg * 4];   // 4 batch rows
                acc[0][0] += hv.x * wv.x; acc[1][0] += hv.x * wv.y; acc[2][0] += hv.x * wv.z; acc[3][0] += hv.x * wv.w;
                acc[0][1] += hv.y * wv.x; acc[1][1] += hv.y * wv.y; acc[2][1] += hv.y * wv.z; acc[3][1] += hv.y * wv.w;
                acc[0][2] += hv.z * wv.x; acc[1][2] += hv.z * wv.y; acc[2][2] += hv.z * wv.z; acc[3][2] += hv.z * wv.w;
                acc[0][3] += hv.w * wv.x; acc[1][3] += hv.w * wv.y; acc[2][3] += hv.w * wv.z; acc[3][3] += hv.w * wv.w;
            }
        }
    }

    // ---- epilogue: spiking neuron update, per (b, kg)
    const float a_out = expf(-0.01f);             // output-neuron leak, tau_m = 1

    #pragma unroll
    for (int j = 0; j < 4; j++) {
        int b = bg * 4 + j;
        size_t sidx = ((size_t)b * IC + i) * NDIM + kg;

        float jg = tanhf(acc[0][j]);
        float ig = sigf(acc[1][j]);
        float fg = sigf(acc[2][j]);
        float og = sigf(acc[3][j]);

        float alpha_m = expf(-7.8125e-5f * jg);     // exp(-(dt/tau_m)*0.5*j)
        float ro      = expf(-1.5625e-4f * ig);     // exp(-(dt/tau_adp)*0.5*i)
        float b_ad    = ro * 0.1f + (1.0f - ro) * ig;
        float Bth     = 0.04f + 1.8f * b_ad;

        float hprev = 0.0f, cprev = 0.0f;
        if (t > 0) {
            hprev = out[((size_t)(b * TT + (t - 1)) * IC + i) * NDIM + kg];
            cprev = cfin[sidx];
        }

        float mem   = jg * alpha_m + (1.0f - alpha_m) * hprev - Bth * ig * 0.01f;
        float spike = (mem - Bth) > 0.0f ? 1.0f : 0.0f;
        float mem_o = mem * a_out + (1.0f - a_out) * spike + 0.08f;

        float cn = cprev * fg + ig * spike * mem_o;
        float hn = og * tanhf(cn);

        cfin[sidx] = cn;
        out[((size_t)(b * TT + t) * IC + i) * NDIM + kg] = hn;
        if (t == TT - 1) hfin[sidx] = hn;
    }
}

extern "C" void kernel_launch(void* const* d_in, const int* in_sizes, int n_in,
                              void* d_out, int out_size, void* d_ws, size_t ws_size,
                              hipStream_t stream) {
    const float* x   = (const float*)d_in[0];
    const float* Uj  = (const float*)d_in[1];
    const float* Ui_ = (const float*)d_in[2];
    const float* Uf  = (const float*)d_in[3];
    const float* Uo  = (const float*)d_in[4];
    const float* Wj  = (const float*)d_in[5];
    const float* Wi  = (const float*)d_in[6];
    const float* Wf  = (const float*)d_in[7];
    const float* Wo  = (const float*)d_in[8];
    const float* bj  = (const float*)d_in[9];
    const float* bi_ = (const float*)d_in[10];
    const float* bf_ = (const float*)d_in[11];
    const float* bo  = (const float*)d_in[12];
    float* out = (float*)d_out;

    for (int t = 0; t < TT; t++) {
        step_kernel<<<dim3(IC, NDIM / KT), dim3(256), 0, stream>>>(
            t, x, Uj, Ui_, Uf, Uo, Wj, Wi, Wf, Wo, bj, bi_, bf_, bo, out);
    }
}

// Round 6
// 1608.376 us; speedup vs baseline: 2.7917x; 2.7917x over previous
//
#include <hip/hip_runtime.h>
#include <hip/hip_bf16.h>

typedef __hip_bfloat16 bf16;
typedef __attribute__((ext_vector_type(8))) short short8;
typedef __attribute__((ext_vector_type(4))) float float4v;

#define BSZ 32
#define TT  128
#define IC  16
#define NDIM 512
#define WS_NEED ((size_t)4 * IC * NDIM * NDIM * 2)   // 33.55 MB bf16 packed weights

__device__ __forceinline__ float sigf(float v) { return 1.0f / (1.0f + expf(-v)); }
__device__ __forceinline__ unsigned short f2bfb(float f) {
    bf16 h = __float2bfloat16(f);
    return *reinterpret_cast<unsigned short*>(&h);
}

// ---------------- one-time weight pack: fp32 W -> bf16 MFMA B-fragments ----
// uint4 index = ((blk*16 + kstep)*64 + lane), blk = (g*IC + i)*32 + nt16
// lane frag elems j=0..7:  W_g[i][ kstep*32 + (lane>>4)*8 + j ][ nt16*16 + (lane&15) ]
__global__ void pack_w(const float* __restrict__ Wj, const float* __restrict__ Wi,
                       const float* __restrict__ Wf, const float* __restrict__ Wo,
                       uint4* __restrict__ wpk)
{
    __shared__ float tile[NDIM][17];
    const int blk  = blockIdx.x;
    const int nt16 = blk & 31;
    const int i    = (blk >> 5) & 15;
    const int g    = blk >> 9;
    const float* W = (g == 0) ? Wj : (g == 1) ? Wi : (g == 2) ? Wf : Wo;
    const float* base = W + (size_t)i * NDIM * NDIM + nt16 * 16;
    const int tid = threadIdx.x;

    #pragma unroll
    for (int r = 0; r < 2; r++) {
        int n = tid + r * 256;
        const float4* p = (const float4*)(base + (size_t)n * NDIM);
        float4 v0 = p[0], v1 = p[1], v2 = p[2], v3 = p[3];
        float* d = &tile[n][0];
        d[0]=v0.x; d[1]=v0.y; d[2]=v0.z; d[3]=v0.w;
        d[4]=v1.x; d[5]=v1.y; d[6]=v1.z; d[7]=v1.w;
        d[8]=v2.x; d[9]=v2.y; d[10]=v2.z; d[11]=v2.w;
        d[12]=v3.x; d[13]=v3.y; d[14]=v3.z; d[15]=v3.w;
    }
    __syncthreads();
    #pragma unroll
    for (int p = 0; p < 4; p++) {
        int f = p * 256 + tid;
        int kstep = f >> 6, L = f & 63;
        int quad = L >> 4, col = L & 15;
        int nr = kstep * 32 + quad * 8;
        unsigned u[4];
        #pragma unroll
        for (int w = 0; w < 4; w++) {
            unsigned lo = f2bfb(tile[nr + 2 * w][col]);
            unsigned hi = f2bfb(tile[nr + 2 * w + 1][col]);
            u[w] = lo | (hi << 16);
        }
        wpk[(size_t)blk * 1024 + (size_t)kstep * 64 + L] = make_uint4(u[0], u[1], u[2], u[3]);
    }
}

// ---------------- per-step MFMA kernel ----------------
__launch_bounds__(256)
__global__ void step_mfma(int t,
    const float* __restrict__ x,
    const float* __restrict__ Uj, const float* __restrict__ Ui, const float* __restrict__ Uf, const float* __restrict__ Uo,
    const uint4* __restrict__ wpk,
    const float* __restrict__ bj, const float* __restrict__ bi, const float* __restrict__ bfp, const float* __restrict__ bo,
    float* __restrict__ out)
{
    __shared__ bf16 h_lds[BSZ][NDIM + 8];   // row stride 520 bf16 = 1040 B

    const int i   = blockIdx.x;        // channel
    const int kt  = blockIdx.y;        // 32-col tile
    const int tid = threadIdx.x;
    const int wid = tid >> 6, L = tid & 63;
    const int quad = L >> 4, c15 = L & 15;
    const int nt16 = kt * 2 + (wid & 1);   // 16-col tile owned by this wave
    const int Mh   = (wid >> 1) * 16;      // batch half

    float* hfin = out + (size_t)BSZ * TT * IC * NDIM;
    float* cfin = hfin + (size_t)BSZ * IC * NDIM;

    float4v acc0 = {0,0,0,0}, acc1 = {0,0,0,0}, acc2 = {0,0,0,0}, acc3 = {0,0,0,0};

    if (t > 0) {
        // ---- stage h[:, t-1] (fp32 in out) -> bf16 LDS, coalesced
        {
            int b = tid >> 3, n0 = (tid & 7) * 64;
            const float4* src = (const float4*)(out + ((size_t)(b * TT + (t - 1)) * IC + i) * NDIM + n0);
            #pragma unroll
            for (int q = 0; q < 8; q++) {
                float4 a = src[2 * q], bb = src[2 * q + 1];
                unsigned u0 = f2bfb(a.x) | ((unsigned)f2bfb(a.y) << 16);
                unsigned u1 = f2bfb(a.z) | ((unsigned)f2bfb(a.w) << 16);
                unsigned u2 = f2bfb(bb.x) | ((unsigned)f2bfb(bb.y) << 16);
                unsigned u3 = f2bfb(bb.z) | ((unsigned)f2bfb(bb.w) << 16);
                *(uint4*)&h_lds[b][n0 + q * 8] = make_uint4(u0, u1, u2, u3);
            }
        }
        __syncthreads();

        const size_t gstride = (size_t)IC * 32 * 1024;                    // uint4s per gate
        const uint4* bbase = wpk + ((size_t)i * 32 + nt16) * 1024 + L;    // gate 0 base
        const bf16* arow = &h_lds[Mh + c15][0];

        #pragma unroll 4
        for (int ks = 0; ks < 16; ks++) {
            short8 a  = *(const short8*)(arow + ks * 32 + quad * 8);
            short8 b0 = *(const short8*)(bbase + (size_t)ks * 64);
            short8 b1 = *(const short8*)(bbase + gstride + (size_t)ks * 64);
            short8 b2 = *(const short8*)(bbase + 2 * gstride + (size_t)ks * 64);
            short8 b3 = *(const short8*)(bbase + 3 * gstride + (size_t)ks * 64);
            acc0 = __builtin_amdgcn_mfma_f32_16x16x32_bf16(a, b0, acc0, 0, 0, 0);
            acc1 = __builtin_amdgcn_mfma_f32_16x16x32_bf16(a, b1, acc1, 0, 0, 0);
            acc2 = __builtin_amdgcn_mfma_f32_16x16x32_bf16(a, b2, acc2, 0, 0, 0);
            acc3 = __builtin_amdgcn_mfma_f32_16x16x32_bf16(a, b3, acc3, 0, 0, 0);
        }
    }

    // ---- epilogue (all 4 gates resident in this wave's acc regs)
    const float a_out = 0.990049834f;     // exp(-0.01)
    const int n = nt16 * 16 + c15;
    const size_t un = (size_t)i * NDIM + n;
    float u0 = Uj[un], u1 = Ui[un], u2 = Uf[un], u3 = Uo[un];
    float c0 = bj[un], c1 = bi[un], c2 = bfp[un], c3 = bo[un];

    #pragma unroll
    for (int r = 0; r < 4; r++) {
        int b = Mh + quad * 4 + r;        // C-layout row
        size_t sidx = ((size_t)b * IC + i) * NDIM + n;
        float xv = x[(size_t)(b * TT + t) * IC + i];

        float jg = tanhf(acc0[r] + c0 + xv * u0);
        float ig = sigf (acc1[r] + c1 + xv * u1);
        float fg = sigf (acc2[r] + c2 + xv * u2);
        float og = sigf (acc3[r] + c3 + xv * u3);

        float alpha_m = expf(-7.8125e-5f * jg);
        float ro      = expf(-1.5625e-4f * ig);
        float b_ad    = ro * 0.1f + (1.0f - ro) * ig;
        float Bth     = 0.04f + 1.8f * b_ad;

        float hprev = 0.0f, cprev = 0.0f;
        if (t > 0) {
            hprev = __bfloat162float(h_lds[b][n]);   // coeff (1-alpha)~7.8e-5: bf16 is free
            cprev = cfin[sidx];
        }

        float mem   = jg * alpha_m + (1.0f - alpha_m) * hprev - Bth * ig * 0.01f;
        float spike = (mem - Bth) > 0.0f ? 1.0f : 0.0f;
        float mem_o = mem * a_out + (1.0f - a_out) * spike + 0.08f;

        float cn = cprev * fg + ig * spike * mem_o;
        float hn = og * tanhf(cn);

        cfin[sidx] = cn;
        out[((size_t)(b * TT + t) * IC + i) * NDIM + n] = hn;
        if (t == TT - 1) hfin[sidx] = hn;
    }
}

// ---------------- fallback (proven R5 path, used only if ws too small) ----
#define KT 32
#define NC 64
__launch_bounds__(256)
__global__ void step_kernel_valu(int t,
    const float* __restrict__ x,
    const float* __restrict__ Uj, const float* __restrict__ Ui, const float* __restrict__ Uf, const float* __restrict__ Uo,
    const float* __restrict__ Wj, const float* __restrict__ Wi, const float* __restrict__ Wf, const float* __restrict__ Wo,
    const float* __restrict__ bj, const float* __restrict__ bi, const float* __restrict__ bfp, const float* __restrict__ bo,
    float* __restrict__ out)
{
    __shared__ float w_lds[NC][KT * 4 + 4];
    __shared__ float h_lds[NC][BSZ + 4];
    const int i = blockIdx.x, k0 = blockIdx.y * KT, tid = threadIdx.x;
    const int kl = tid & 31, bg = tid >> 5, kg = k0 + kl;
    float* hfin = out + (size_t)BSZ * TT * IC * NDIM;
    float* cfin = hfin + (size_t)BSZ * IC * NDIM;
    float acc[4][4];
    {
        size_t uidx = (size_t)i * NDIM + kg;
        float u0 = Uj[uidx], u1 = Ui[uidx], u2 = Uf[uidx], u3 = Uo[uidx];
        float c0 = bj[uidx], c1 = bi[uidx], c2 = bfp[uidx], c3 = bo[uidx];
        #pragma unroll
        for (int j = 0; j < 4; j++) {
            int b = bg * 4 + j;
            float xv = x[(size_t)(b * TT + t) * IC + i];
            acc[0][j] = c0 + xv * u0; acc[1][j] = c1 + xv * u1;
            acc[2][j] = c2 + xv * u2; acc[3][j] = c3 + xv * u3;
        }
    }
    if (t > 0) {
        for (int n0 = 0; n0 < NDIM; n0 += NC) {
            __syncthreads();
            {
                int g = tid >> 6, nn = tid & 63;
                const float* Wp = (g == 0) ? Wj : (g == 1) ? Wi : (g == 2) ? Wf : Wo;
                const float4* p = (const float4*)(Wp + ((size_t)i * NDIM + (size_t)(n0 + nn)) * NDIM + k0);
                #pragma unroll
                for (int q = 0; q < 8; q++) {
                    float4 v = p[q];
                    w_lds[nn][(q * 4 + 0) * 4 + g] = v.x; w_lds[nn][(q * 4 + 1) * 4 + g] = v.y;
                    w_lds[nn][(q * 4 + 2) * 4 + g] = v.z; w_lds[nn][(q * 4 + 3) * 4 + g] = v.w;
                }
            }
            {
                int b = tid >> 3, nb = (tid & 7) * 8;
                const float4* ph = (const float4*)(out + ((size_t)(b * TT + (t - 1)) * IC + i) * NDIM + n0 + nb);
                float4 h0 = ph[0], h1 = ph[1];
                h_lds[nb + 0][b] = h0.x; h_lds[nb + 1][b] = h0.y; h_lds[nb + 2][b] = h0.z; h_lds[nb + 3][b] = h0.w;
                h_lds[nb + 4][b] = h1.x; h_lds[nb + 5][b] = h1.y; h_lds[nb + 6][b] = h1.z; h_lds[nb + 7][b] = h1.w;
            }
            __syncthreads();
            #pragma unroll 8
            for (int nn = 0; nn < NC; nn++) {
                float4 wv = *(const float4*)&w_lds[nn][kl * 4];
                float4 hv = *(const float4*)&h_lds[nn][bg * 4];
                acc[0][0] += hv.x * wv.x; acc[1][0] += hv.x * wv.y; acc[2][0] += hv.x * wv.z; acc[3][0] += hv.x * wv.w;
                acc[0][1] += hv.y * wv.x; acc[1][1] += hv.y * wv.y; acc[2][1] += hv.y * wv.z; acc[3][1] += hv.y * wv.w;
                acc[0][2] += hv.z * wv.x; acc[1][2] += hv.z * wv.y; acc[2][2] += hv.z * wv.z; acc[3][2] += hv.z * wv.w;
                acc[0][3] += hv.w * wv.x; acc[1][3] += hv.w * wv.y; acc[2][3] += hv.w * wv.z; acc[3][3] += hv.w * wv.w;
            }
        }
    }
    const float a_out = 0.990049834f;
    #pragma unroll
    for (int j = 0; j < 4; j++) {
        int b = bg * 4 + j;
        size_t sidx = ((size_t)b * IC + i) * NDIM + kg;
        float jg = tanhf(acc[0][j]), ig = sigf(acc[1][j]), fg = sigf(acc[2][j]), og = sigf(acc[3][j]);
        float alpha_m = expf(-7.8125e-5f * jg);
        float ro = expf(-1.5625e-4f * ig);
        float b_ad = ro * 0.1f + (1.0f - ro) * ig;
        float Bth = 0.04f + 1.8f * b_ad;
        float hprev = 0.0f, cprev = 0.0f;
        if (t > 0) { hprev = out[((size_t)(b * TT + (t - 1)) * IC + i) * NDIM + kg]; cprev = cfin[sidx]; }
        float mem = jg * alpha_m + (1.0f - alpha_m) * hprev - Bth * ig * 0.01f;
        float spike = (mem - Bth) > 0.0f ? 1.0f : 0.0f;
        float mem_o = mem * a_out + (1.0f - a_out) * spike + 0.08f;
        float cn = cprev * fg + ig * spike * mem_o;
        float hn = og * tanhf(cn);
        cfin[sidx] = cn;
        out[((size_t)(b * TT + t) * IC + i) * NDIM + kg] = hn;
        if (t == TT - 1) hfin[sidx] = hn;
    }
}

extern "C" void kernel_launch(void* const* d_in, const int* in_sizes, int n_in,
                              void* d_out, int out_size, void* d_ws, size_t ws_size,
                              hipStream_t stream) {
    const float* x   = (const float*)d_in[0];
    const float* Uj  = (const float*)d_in[1];
    const float* Ui_ = (const float*)d_in[2];
    const float* Uf  = (const float*)d_in[3];
    const float* Uo  = (const float*)d_in[4];
    const float* Wj  = (const float*)d_in[5];
    const float* Wi  = (const float*)d_in[6];
    const float* Wf  = (const float*)d_in[7];
    const float* Wo  = (const float*)d_in[8];
    const float* bj  = (const float*)d_in[9];
    const float* bi_ = (const float*)d_in[10];
    const float* bf_ = (const float*)d_in[11];
    const float* bo  = (const float*)d_in[12];
    float* out = (float*)d_out;

    if (ws_size >= WS_NEED) {
        pack_w<<<dim3(2048), dim3(256), 0, stream>>>(Wj, Wi, Wf, Wo, (uint4*)d_ws);
        for (int t = 0; t < TT; t++) {
            step_mfma<<<dim3(IC, 16), dim3(256), 0, stream>>>(
                t, x, Uj, Ui_, Uf, Uo, (const uint4*)d_ws, bj, bi_, bf_, bo, out);
        }
    } else {
        for (int t = 0; t < TT; t++) {
            step_kernel_valu<<<dim3(IC, NDIM / KT), dim3(256), 0, stream>>>(
                t, x, Uj, Ui_, Uf, Uo, Wj, Wi, Wf, Wo, bj, bi_, bf_, bo, out);
        }
    }
}